// Round 1
// baseline (1062.298 us; speedup 1.0000x reference)
//
#include <hip/hip_runtime.h>
#include <hip/hip_bf16.h>
#include <math.h>

#define LATENT 256
#define HIDDEN 512
#define NFD    64
#define MAXN   50
#define BATCH  128
#define NPAIR  2450   // 50*49

__device__ __forceinline__ float sigmoidf_(float x) {
    return 1.0f / (1.0f + expf(-x));
}

// ---------------------------------------------------------------------------
// Generic C[M,N] = epi(A[M,K] @ B[N,K]^T + bias)
// A row-major (lda), B row-major (ldb)  -> "NT" gemm.
// EPI: 0 = none, 1 = relu, 2 = raw->C and sigmoid->C2
// Tile 64x64, 256 threads, 4x4 per thread. K % 16 == 0, N % 64 == 0.
// ---------------------------------------------------------------------------
template <int EPI>
__global__ __launch_bounds__(256) void gemm_nt(
    const float* __restrict__ A, int lda,
    const float* __restrict__ B, int ldb,
    const float* __restrict__ bias,
    float* __restrict__ C, int ldc,
    float* __restrict__ C2,
    int M, int N, int K)
{
    __shared__ __align__(16) float As[16][68];
    __shared__ __align__(16) float Bs[16][68];

    const int tid = threadIdx.x;
    const int m0 = blockIdx.y * 64;
    const int n0 = blockIdx.x * 64;

    const int sr = tid >> 2;          // 0..63 : row (A) / col (B) within tile
    const int kc = (tid & 3) * 4;     // k-chunk base (float4)

    const int tx = tid & 15;
    const int ty = tid >> 4;

    float acc[4][4] = {};

    for (int k0 = 0; k0 < K; k0 += 16) {
        // stage A tile (64 m x 16 k), transposed into As[k][m]
        float4 a4 = make_float4(0.f, 0.f, 0.f, 0.f);
        int gm = m0 + sr;
        if (gm < M) a4 = *(const float4*)&A[(size_t)gm * lda + k0 + kc];
        As[kc + 0][sr] = a4.x; As[kc + 1][sr] = a4.y;
        As[kc + 2][sr] = a4.z; As[kc + 3][sr] = a4.w;

        // stage B tile (64 n x 16 k) into Bs[k][n]
        float4 b4 = *(const float4*)&B[(size_t)(n0 + sr) * ldb + k0 + kc];
        Bs[kc + 0][sr] = b4.x; Bs[kc + 1][sr] = b4.y;
        Bs[kc + 2][sr] = b4.z; Bs[kc + 3][sr] = b4.w;

        __syncthreads();

        #pragma unroll
        for (int k = 0; k < 16; ++k) {
            float av[4], bv[4];
            *(float4*)av = *(const float4*)&As[k][ty * 4];
            *(float4*)bv = *(const float4*)&Bs[k][tx * 4];
            #pragma unroll
            for (int r = 0; r < 4; ++r)
                #pragma unroll
                for (int c = 0; c < 4; ++c)
                    acc[r][c] = fmaf(av[r], bv[c], acc[r][c]);
        }
        __syncthreads();
    }

    #pragma unroll
    for (int r = 0; r < 4; ++r) {
        int gm = m0 + ty * 4 + r;
        if (gm >= M) continue;
        #pragma unroll
        for (int c = 0; c < 4; ++c) {
            int gn = n0 + tx * 4 + c;
            float v = acc[r][c];
            if (bias) v += bias[gn];
            if (EPI == 1) v = fmaxf(v, 0.f);
            C[(size_t)gm * ldc + gn] = v;
            if (EPI == 2) C2[(size_t)gm * ldc + gn] = sigmoidf_(v);
        }
    }
}

// ---------------------------------------------------------------------------
// Fused edge kernel.
// For batch b (blockIdx.y), 64 pairs per block (blockIdx.x):
//   e1[p,k] = relu(Abc[b,k] + Ui[b,i(p),k] + Uj[b,j(p),k])      (k<512)
//   e2[p,g] = relu(sum_k e1[p,k]*E2[g,k] + c2[g])               (g<256)
//   out[b,p] = sigmoid(sum_g e2[p,g]*E3[g] + c3)
// Block: 256 threads, tile 64(M) x 256(N), per-thread 4x16 accumulators.
// ---------------------------------------------------------------------------
__global__ __launch_bounds__(256) void edge_kernel(
    const float* __restrict__ Abc,   // [B,512]  (z@E1z^T + c1)
    const float* __restrict__ Ui,    // [B,50,512]
    const float* __restrict__ Uj,    // [B,50,512]
    const float* __restrict__ E2,    // [256,512]
    const float* __restrict__ c2,    // [256]
    const float* __restrict__ E3,    // [256]
    const float* __restrict__ c3p,   // [1]
    float* __restrict__ outE)        // [B,2450]
{
    __shared__ __align__(16) float As[16][68];
    __shared__ __align__(16) float Bs[16][260];
    __shared__ __align__(16) float abc_s[512];
    __shared__ float c2_s[256];
    __shared__ float e3_s[256];
    __shared__ int   ii_s[64];
    __shared__ int   jj_s[64];
    __shared__ float red[64][17];

    const int b  = blockIdx.y;
    const int p0 = blockIdx.x * 64;
    const int tid = threadIdx.x;

    // preload per-block constants
    abc_s[tid]       = Abc[b * 512 + tid];
    abc_s[tid + 256] = Abc[b * 512 + tid + 256];
    c2_s[tid] = c2[tid];
    e3_s[tid] = E3[tid];
    if (tid < 64) {
        int p = p0 + tid;
        int i = 0, j = 0;
        if (p < NPAIR) {
            i = p / 49;
            int kk = p - i * 49;
            j = kk + (kk >= i ? 1 : 0);
        }
        ii_s[tid] = i;
        jj_s[tid] = j;
    }
    __syncthreads();

    const int tx = tid & 15;
    const int ty = tid >> 4;
    const int sr = tid >> 2;          // 0..63
    const int kc = (tid & 3) * 4;     // k-chunk

    const float* UiB = Ui + (size_t)b * MAXN * 512;
    const float* UjB = Uj + (size_t)b * MAXN * 512;

    float acc[4][16] = {};   // rows: ty*4+r ; cols: tx*4 + 64*q + c

    const int myI = ii_s[sr];
    const int myJ = jj_s[sr];
    const bool rowOK = (p0 + sr) < NPAIR;

    for (int k0 = 0; k0 < 512; k0 += 16) {
        // stage A tile: e1 built on the fly (1 float4 per thread)
        float4 u = make_float4(0.f, 0.f, 0.f, 0.f);
        if (rowOK) {
            float4 a = *(const float4*)&abc_s[k0 + kc];
            float4 ui = *(const float4*)&UiB[myI * 512 + k0 + kc];
            float4 uj = *(const float4*)&UjB[myJ * 512 + k0 + kc];
            u.x = fmaxf(a.x + ui.x + uj.x, 0.f);
            u.y = fmaxf(a.y + ui.y + uj.y, 0.f);
            u.z = fmaxf(a.z + ui.z + uj.z, 0.f);
            u.w = fmaxf(a.w + ui.w + uj.w, 0.f);
        }
        As[kc + 0][sr] = u.x; As[kc + 1][sr] = u.y;
        As[kc + 2][sr] = u.z; As[kc + 3][sr] = u.w;

        // stage B tile: E2 (16 k x 256 n), 4 float4 per thread
        #pragma unroll
        for (int i4 = 0; i4 < 4; ++i4) {
            int n = sr + 64 * i4;
            float4 b4 = *(const float4*)&E2[n * 512 + k0 + kc];
            Bs[kc + 0][n] = b4.x; Bs[kc + 1][n] = b4.y;
            Bs[kc + 2][n] = b4.z; Bs[kc + 3][n] = b4.w;
        }
        __syncthreads();

        #pragma unroll
        for (int k = 0; k < 16; ++k) {
            float av[4];
            *(float4*)av = *(const float4*)&As[k][ty * 4];
            #pragma unroll
            for (int q = 0; q < 4; ++q) {
                float bv[4];
                *(float4*)bv = *(const float4*)&Bs[k][tx * 4 + 64 * q];
                #pragma unroll
                for (int r = 0; r < 4; ++r)
                    #pragma unroll
                    for (int c = 0; c < 4; ++c)
                        acc[r][q * 4 + c] = fmaf(av[r], bv[c], acc[r][q * 4 + c]);
            }
        }
        __syncthreads();
    }

    // epilogue: e2 = relu(acc + c2), partial dot with E3
    float part[4] = {0.f, 0.f, 0.f, 0.f};
    #pragma unroll
    for (int q = 0; q < 4; ++q) {
        #pragma unroll
        for (int c = 0; c < 4; ++c) {
            int n = tx * 4 + 64 * q + c;
            float w  = e3_s[n];
            float bb = c2_s[n];
            #pragma unroll
            for (int r = 0; r < 4; ++r) {
                float v = fmaxf(acc[r][q * 4 + c] + bb, 0.f);
                part[r] = fmaf(v, w, part[r]);
            }
        }
    }
    #pragma unroll
    for (int r = 0; r < 4; ++r) red[ty * 4 + r][tx] = part[r];
    __syncthreads();

    if (tid < 64) {
        int p = p0 + tid;
        if (p < NPAIR) {
            float s = 0.f;
            #pragma unroll
            for (int t = 0; t < 16; ++t) s += red[tid][t];
            outE[(size_t)b * NPAIR + p] = sigmoidf_(s + c3p[0]);
        }
    }
}

// ---------------------------------------------------------------------------
extern "C" void kernel_launch(void* const* d_in, const int* in_sizes, int n_in,
                              void* d_out, int out_size, void* d_ws, size_t ws_size,
                              hipStream_t stream)
{
    const float* z  = (const float*)d_in[0];
    const float* W1 = (const float*)d_in[1];
    const float* b1 = (const float*)d_in[2];
    const float* W2 = (const float*)d_in[3];
    const float* b2 = (const float*)d_in[4];
    const float* W3 = (const float*)d_in[5];
    const float* b3 = (const float*)d_in[6];
    const float* E1 = (const float*)d_in[7];
    const float* c1 = (const float*)d_in[8];
    const float* E2 = (const float*)d_in[9];
    const float* c2 = (const float*)d_in[10];
    const float* E3 = (const float*)d_in[11];
    const float* c3 = (const float*)d_in[12];

    float* out = (float*)d_out;
    float* ws  = (float*)d_ws;

    // workspace layout (floats)
    float* h1  = ws;                    // 128*512
    float* h2  = h1 + 128 * 512;        // 128*512
    float* nf  = h2 + 128 * 512;        // 128*3200
    float* Abc = nf + 128 * 3200;       // 128*512
    float* Ui  = Abc + 128 * 512;       // 128*50*512
    float* Uj  = Ui + 128 * 50 * 512;   // 128*50*512

    dim3 blk(256);

    // node MLP
    gemm_nt<1><<<dim3(512 / 64, 128 / 64), blk, 0, stream>>>(
        z, LATENT, W1, LATENT, b1, h1, HIDDEN, nullptr, BATCH, HIDDEN, LATENT);
    gemm_nt<1><<<dim3(512 / 64, 128 / 64), blk, 0, stream>>>(
        h1, HIDDEN, W2, HIDDEN, b2, h2, HIDDEN, nullptr, BATCH, HIDDEN, HIDDEN);
    // nf (raw, with bias) -> ws ; sigmoid(nf) -> out[0 : 128*3200)
    gemm_nt<2><<<dim3(3200 / 64, 128 / 64), blk, 0, stream>>>(
        h2, HIDDEN, W3, HIDDEN, b3, nf, 3200, out, BATCH, 3200, HIDDEN);

    // edge-layer-1 decomposition
    gemm_nt<0><<<dim3(512 / 64, 128 / 64), blk, 0, stream>>>(
        z, LATENT, E1, 384, c1, Abc, HIDDEN, nullptr, BATCH, HIDDEN, LATENT);
    gemm_nt<0><<<dim3(512 / 64, 6400 / 64), blk, 0, stream>>>(
        nf, NFD, E1 + 256, 384, nullptr, Ui, HIDDEN, nullptr, BATCH * MAXN, HIDDEN, NFD);
    gemm_nt<0><<<dim3(512 / 64, 6400 / 64), blk, 0, stream>>>(
        nf, NFD, E1 + 320, 384, nullptr, Uj, HIDDEN, nullptr, BATCH * MAXN, HIDDEN, NFD);

    // fused edge MLP (e1 -> e2 -> E3 dot -> sigmoid)
    edge_kernel<<<dim3((NPAIR + 63) / 64, BATCH), blk, 0, stream>>>(
        Abc, Ui, Uj, E2, c2, E3, c3, out + BATCH * MAXN * NFD);
}

// Round 2
// 300.918 us; speedup vs baseline: 3.5302x; 3.5302x over previous
//
#include <hip/hip_runtime.h>
#include <hip/hip_bf16.h>
#include <math.h>

#define LATENT 256
#define HIDDEN 512
#define NFD    64
#define MAXN   50
#define BATCH  128
#define NPAIR  2450   // 50*49
#define PTILE  128
#define NTILES 20     // ceil(2450/128)

typedef __attribute__((ext_vector_type(8))) short bf16x8;
typedef __attribute__((ext_vector_type(4))) float f32x4;
typedef __attribute__((ext_vector_type(4))) unsigned short us4;

__device__ __forceinline__ float sigmoidf_(float x) {
    return 1.0f / (1.0f + expf(-x));
}
__device__ __forceinline__ unsigned short f2b(float f) {   // fp32 -> bf16 RNE
    unsigned u = __builtin_bit_cast(unsigned, f);
    u += 0x7FFFu + ((u >> 16) & 1u);
    return (unsigned short)(u >> 16);
}
__device__ __forceinline__ float b2f(short s) {
    unsigned u = ((unsigned)(unsigned short)s) << 16;
    return __builtin_bit_cast(float, u);
}

// ---------------------------------------------------------------------------
// fp32 -> bf16 bulk convert (n % 4 == 0)
// ---------------------------------------------------------------------------
__global__ __launch_bounds__(256) void cvt_bf16_kernel(
    const float* __restrict__ in, unsigned short* __restrict__ out, int n)
{
    int i = (blockIdx.x * 256 + threadIdx.x) * 4;
    if (i < n) {
        float4 v = *(const float4*)&in[i];
        us4 o;
        o[0] = f2b(v.x); o[1] = f2b(v.y); o[2] = f2b(v.z); o[3] = f2b(v.w);
        *(us4*)&out[i] = o;
    }
}

// ---------------------------------------------------------------------------
// C[M,N] = epi(A[M,K] @ B[N,K]^T + bias)   (fp32 compute)
// EPI: 0 none->C ; 1 relu->C ; 2 raw->C + sigmoid->C2 ;
//      3 bf16->Cb ; 4 bf16(v + add[(gm/50)*512 + gn])->Cb
// Tile 64x64, 256 threads, 4x4/thread. K%16==0, N%64==0.
// ---------------------------------------------------------------------------
template <int EPI>
__global__ __launch_bounds__(256) void gemm_nt(
    const float* __restrict__ A, int lda,
    const float* __restrict__ B, int ldb,
    const float* __restrict__ bias,
    float* __restrict__ C, int ldc,
    float* __restrict__ C2,
    unsigned short* __restrict__ Cb,
    const float* __restrict__ add,
    int M, int N, int K)
{
    __shared__ __align__(16) float As[16][68];
    __shared__ __align__(16) float Bs[16][68];

    const int tid = threadIdx.x;
    const int m0 = blockIdx.y * 64;
    const int n0 = blockIdx.x * 64;

    const int sr = tid >> 2;
    const int kc = (tid & 3) * 4;
    const int tx = tid & 15;
    const int ty = tid >> 4;

    float acc[4][4] = {};

    for (int k0 = 0; k0 < K; k0 += 16) {
        float4 a4 = make_float4(0.f, 0.f, 0.f, 0.f);
        int gm = m0 + sr;
        if (gm < M) a4 = *(const float4*)&A[(size_t)gm * lda + k0 + kc];
        As[kc + 0][sr] = a4.x; As[kc + 1][sr] = a4.y;
        As[kc + 2][sr] = a4.z; As[kc + 3][sr] = a4.w;

        float4 b4 = *(const float4*)&B[(size_t)(n0 + sr) * ldb + k0 + kc];
        Bs[kc + 0][sr] = b4.x; Bs[kc + 1][sr] = b4.y;
        Bs[kc + 2][sr] = b4.z; Bs[kc + 3][sr] = b4.w;

        __syncthreads();

        #pragma unroll
        for (int k = 0; k < 16; ++k) {
            float av[4], bv[4];
            *(float4*)av = *(const float4*)&As[k][ty * 4];
            *(float4*)bv = *(const float4*)&Bs[k][tx * 4];
            #pragma unroll
            for (int r = 0; r < 4; ++r)
                #pragma unroll
                for (int c = 0; c < 4; ++c)
                    acc[r][c] = fmaf(av[r], bv[c], acc[r][c]);
        }
        __syncthreads();
    }

    #pragma unroll
    for (int r = 0; r < 4; ++r) {
        int gm = m0 + ty * 4 + r;
        if (gm >= M) continue;
        #pragma unroll
        for (int c = 0; c < 4; ++c) {
            int gn = n0 + tx * 4 + c;
            float v = acc[r][c];
            if (bias) v += bias[gn];
            if (EPI == 1) v = fmaxf(v, 0.f);
            if (EPI <= 2) {
                C[(size_t)gm * ldc + gn] = v;
                if (EPI == 2) C2[(size_t)gm * ldc + gn] = sigmoidf_(v);
            } else {
                if (EPI == 4) v += add[(size_t)(gm / 50) * HIDDEN + gn];
                Cb[(size_t)gm * ldc + gn] = f2b(v);
            }
        }
    }
}

// ---------------------------------------------------------------------------
// MFMA edge kernel.  Per block: batch b, 128 pairs x 256 g, K=512.
//   e1[p,k] = relu(Ui'[i(p),k] + Uj[j(p),k])          (Ui' already has Abc)
//   e2[p,g] = relu(e1 @ E2^T + c2) ; out = sigmoid(e2 @ E3 + c3)
// 512 thr = 8 waves (2 wr x 4 wc), each wave 64x64 via 4x4 mfma 16x16x32.
// A-tile (e1) built per 32-wide k-step into double-buffered LDS (bf16);
// B frags (E2 bf16) from global with 1-step register prefetch.
// ---------------------------------------------------------------------------
__global__ __launch_bounds__(512) void edge_mfma(
    const unsigned short* __restrict__ Ui,   // [B,50,512] bf16 (incl. Abc)
    const unsigned short* __restrict__ Uj,   // [B,50,512] bf16
    const unsigned short* __restrict__ E2b,  // [256,512] bf16
    const float* __restrict__ c2,
    const float* __restrict__ E3,
    const float* __restrict__ c3p,
    float* __restrict__ outE)                // [B,2450]
{
    __shared__ unsigned short As[2][PTILE * 40];   // row stride 40 shorts (80B)
    __shared__ float c2_s[256], e3_s[256];
    __shared__ int   ii_s[PTILE], jj_s[PTILE];
    __shared__ float red[PTILE][5];

    const int b   = blockIdx.y;
    const int p0  = blockIdx.x * PTILE;
    const int tid = threadIdx.x;
    const int lane = tid & 63;
    const int wid  = tid >> 6;
    const int wr = wid >> 2;     // 0..1
    const int wc = wid & 3;      // 0..3
    const int ln = lane & 15;
    const int hi = lane >> 4;

    if (tid < 256) { c2_s[tid] = c2[tid]; e3_s[tid] = E3[tid]; }
    if (tid < PTILE) {
        int p = p0 + tid;
        int i = 0, j = 0;
        if (p < NPAIR) {
            i = p / 49;
            int kk = p - i * 49;
            j = kk + (kk >= i ? 1 : 0);
        }
        ii_s[tid] = i;
        jj_s[tid] = j;
    }
    __syncthreads();

    const unsigned short* UiB = Ui + (size_t)b * MAXN * 512;
    const unsigned short* UjB = Uj + (size_t)b * MAXN * 512;

    // staging role: thread -> (row, 8-col chunk) of the 128x32 k-step tile
    const int srow = tid >> 2;
    const int scol = (tid & 3) * 8;
    const size_t gUi = (size_t)ii_s[srow] * 512 + scol;
    const size_t gUj = (size_t)jj_s[srow] * 512 + scol;
    const int sdst = srow * 40 + scol;

    const unsigned short* E2l = E2b + ((64 * wc + ln) * 512 + 8 * hi);
    const int abase = (64 * wr + ln) * 40 + 8 * hi;

    f32x4 acc[4][4] = {};

    // prologue: stage k-step 0, prefetch B frags for k-step 0
    {
        bf16x8 ui = *(const bf16x8*)(UiB + gUi);
        bf16x8 uj = *(const bf16x8*)(UjB + gUj);
        bf16x8 o;
        #pragma unroll
        for (int e = 0; e < 8; ++e)
            o[e] = (short)f2b(fmaxf(b2f(ui[e]) + b2f(uj[e]), 0.f));
        *(bf16x8*)&As[0][sdst] = o;
    }
    bf16x8 bcur[4];
    #pragma unroll
    for (int ni = 0; ni < 4; ++ni)
        bcur[ni] = *(const bf16x8*)(E2l + ni * 16 * 512);
    __syncthreads();

    for (int ks = 0; ks < 16; ++ks) {
        const int cur = ks & 1;
        const int k0n = (ks + 1) * 32;
        bf16x8 ui, uj, bnxt[4];
        if (ks < 15) {
            ui = *(const bf16x8*)(UiB + gUi + k0n);
            uj = *(const bf16x8*)(UjB + gUj + k0n);
            #pragma unroll
            for (int ni = 0; ni < 4; ++ni)
                bnxt[ni] = *(const bf16x8*)(E2l + ni * 16 * 512 + k0n);
        }
        bf16x8 af[4];
        #pragma unroll
        for (int mi = 0; mi < 4; ++mi)
            af[mi] = *(const bf16x8*)&As[cur][abase + mi * 16 * 40];
        #pragma unroll
        for (int mi = 0; mi < 4; ++mi)
            #pragma unroll
            for (int ni = 0; ni < 4; ++ni)
                acc[mi][ni] = __builtin_amdgcn_mfma_f32_16x16x32_bf16(
                    af[mi], bcur[ni], acc[mi][ni], 0, 0, 0);
        if (ks < 15) {
            bf16x8 o;
            #pragma unroll
            for (int e = 0; e < 8; ++e)
                o[e] = (short)f2b(fmaxf(b2f(ui[e]) + b2f(uj[e]), 0.f));
            *(bf16x8*)&As[cur ^ 1][sdst] = o;
            #pragma unroll
            for (int ni = 0; ni < 4; ++ni) bcur[ni] = bnxt[ni];
        }
        __syncthreads();
    }

    // epilogue: relu(+c2), dot E3, reduce 16 lanes -> LDS -> 4 waves
    const float c3v = c3p[0];
    #pragma unroll
    for (int mi = 0; mi < 4; ++mi) {
        #pragma unroll
        for (int r = 0; r < 4; ++r) {
            float part = 0.f;
            #pragma unroll
            for (int ni = 0; ni < 4; ++ni) {
                int g = 64 * wc + 16 * ni + ln;
                float v = fmaxf(acc[mi][ni][r] + c2_s[g], 0.f);
                part = fmaf(v, e3_s[g], part);
            }
            part += __shfl_xor(part, 1);
            part += __shfl_xor(part, 2);
            part += __shfl_xor(part, 4);
            part += __shfl_xor(part, 8);
            if (ln == 0) red[64 * wr + 16 * mi + 4 * hi + r][wc] = part;
        }
    }
    __syncthreads();

    if (tid < PTILE) {
        int p = p0 + tid;
        if (p < NPAIR) {
            float s = red[tid][0] + red[tid][1] + red[tid][2] + red[tid][3] + c3v;
            outE[(size_t)b * NPAIR + p] = sigmoidf_(s);
        }
    }
}

// ---------------------------------------------------------------------------
extern "C" void kernel_launch(void* const* d_in, const int* in_sizes, int n_in,
                              void* d_out, int out_size, void* d_ws, size_t ws_size,
                              hipStream_t stream)
{
    const float* z  = (const float*)d_in[0];
    const float* W1 = (const float*)d_in[1];
    const float* b1 = (const float*)d_in[2];
    const float* W2 = (const float*)d_in[3];
    const float* b2 = (const float*)d_in[4];
    const float* W3 = (const float*)d_in[5];
    const float* b3 = (const float*)d_in[6];
    const float* E1 = (const float*)d_in[7];
    const float* c1 = (const float*)d_in[8];
    const float* E2 = (const float*)d_in[9];
    const float* c2 = (const float*)d_in[10];
    const float* E3 = (const float*)d_in[11];
    const float* c3 = (const float*)d_in[12];

    float* out = (float*)d_out;
    float* ws  = (float*)d_ws;

    // workspace layout
    float* h1  = ws;                        // 128*512 f32
    float* h2  = h1 + 65536;                // 128*512 f32
    float* nf  = h2 + 65536;                // 128*3200 f32
    float* Abc = nf + 409600;               // 128*512 f32
    unsigned short* Uib = (unsigned short*)(Abc + 65536);   // 128*50*512 bf16
    unsigned short* Ujb = Uib + (size_t)BATCH * MAXN * 512; // 128*50*512 bf16
    unsigned short* E2b = Ujb + (size_t)BATCH * MAXN * 512; // 256*512 bf16

    dim3 blk(256);

    // E2 -> bf16
    cvt_bf16_kernel<<<dim3(131072 / 4 / 256), blk, 0, stream>>>(E2, E2b, 131072);

    // node MLP (fp32)
    gemm_nt<1><<<dim3(8, 2), blk, 0, stream>>>(
        z, LATENT, W1, LATENT, b1, h1, HIDDEN, nullptr, nullptr, nullptr,
        BATCH, HIDDEN, LATENT);
    gemm_nt<1><<<dim3(8, 2), blk, 0, stream>>>(
        h1, HIDDEN, W2, HIDDEN, b2, h2, HIDDEN, nullptr, nullptr, nullptr,
        BATCH, HIDDEN, HIDDEN);
    gemm_nt<2><<<dim3(50, 2), blk, 0, stream>>>(
        h2, HIDDEN, W3, HIDDEN, b3, nf, 3200, out, nullptr, nullptr,
        BATCH, 3200, HIDDEN);

    // Abc = z @ E1z^T + c1 (fp32)
    gemm_nt<0><<<dim3(8, 2), blk, 0, stream>>>(
        z, LATENT, E1, 384, c1, Abc, HIDDEN, nullptr, nullptr, nullptr,
        BATCH, HIDDEN, LATENT);

    // Ui' = bf16(nf @ E1i^T + Abc[b]) ; Uj = bf16(nf @ E1j^T)
    gemm_nt<4><<<dim3(8, 100), blk, 0, stream>>>(
        nf, NFD, E1 + 256, 384, nullptr, nullptr, HIDDEN, nullptr, Uib, Abc,
        BATCH * MAXN, HIDDEN, NFD);
    gemm_nt<3><<<dim3(8, 100), blk, 0, stream>>>(
        nf, NFD, E1 + 320, 384, nullptr, nullptr, HIDDEN, nullptr, Ujb, nullptr,
        BATCH * MAXN, HIDDEN, NFD);

    // fused edge MLP with MFMA
    edge_mfma<<<dim3(NTILES, BATCH), dim3(512), 0, stream>>>(
        Uib, Ujb, E2b, c2, E3, c3, out + BATCH * MAXN * NFD);
}

// Round 3
// 216.160 us; speedup vs baseline: 4.9144x; 1.3921x over previous
//
#include <hip/hip_runtime.h>
#include <hip/hip_bf16.h>
#include <math.h>

#define LATENT 256
#define HIDDEN 512
#define NFD    64
#define MAXN   50
#define BATCH  128
#define NPAIR  2450   // 50*49
#define PTILE  128
#define NTILES 20     // ceil(2450/128)

typedef __attribute__((ext_vector_type(8))) short bf16x8;
typedef __attribute__((ext_vector_type(4))) float f32x4;
typedef __attribute__((ext_vector_type(4))) unsigned int u32x4;

__device__ __forceinline__ float sigmoidf_(float x) {
    return 1.0f / (1.0f + expf(-x));
}
__device__ __forceinline__ unsigned short f2b(float f) {   // fp32 -> bf16 RNE
    unsigned u = __builtin_bit_cast(unsigned, f);
    u += 0x7FFFu + ((u >> 16) & 1u);
    return (unsigned short)(u >> 16);
}
__device__ __forceinline__ float b2f(short s) {
    unsigned u = ((unsigned)(unsigned short)s) << 16;
    return __builtin_bit_cast(float, u);
}
__device__ __forceinline__ unsigned cvt_pk_bf16(float lo, float hi) {
    unsigned r;
    asm("v_cvt_pk_bf16_f32 %0, %1, %2" : "=v"(r) : "v"(lo), "v"(hi));
    return r;
}
// e1 8-elem build: relu(b2f(ui)+b2f(uj)) packed to 4x u32 (8 bf16)
__device__ __forceinline__ u32x4 build_e1(bf16x8 ui, bf16x8 uj) {
    u32x4 o;
    #pragma unroll
    for (int t = 0; t < 4; ++t) {
        float lo = fmaxf(b2f(ui[2 * t])     + b2f(uj[2 * t]),     0.f);
        float hh = fmaxf(b2f(ui[2 * t + 1]) + b2f(uj[2 * t + 1]), 0.f);
        o[t] = cvt_pk_bf16(lo, hh);
    }
    return o;
}

// ---------------------------------------------------------------------------
// E2 [256,512] f32 -> E2t chunk-major bf16: E2t[(kc*256+g)*8 + e] = E2[g][kc*8+e]
// ---------------------------------------------------------------------------
__global__ __launch_bounds__(256) void cvt_e2t(
    const float* __restrict__ E2, unsigned short* __restrict__ E2t)
{
    int idx = blockIdx.x * 256 + threadIdx.x;   // 16384 total
    int g  = idx & 255;
    int kc = idx >> 8;                          // 0..63
    float4 a = *(const float4*)&E2[(size_t)g * 512 + kc * 8];
    float4 b = *(const float4*)&E2[(size_t)g * 512 + kc * 8 + 4];
    u32x4 o;
    o[0] = (unsigned)f2b(a.x) | ((unsigned)f2b(a.y) << 16);
    o[1] = (unsigned)f2b(a.z) | ((unsigned)f2b(a.w) << 16);
    o[2] = (unsigned)f2b(b.x) | ((unsigned)f2b(b.y) << 16);
    o[3] = (unsigned)f2b(b.z) | ((unsigned)f2b(b.w) << 16);
    *(u32x4*)(E2t + (size_t)idx * 8) = o;
}

// ---------------------------------------------------------------------------
// fp32 NT gemm, tile 64x64, 256 thr, 4x4/thread.
// EPI: 1 relu->C ; 2 raw->C + sigmoid->C2
// ---------------------------------------------------------------------------
template <int EPI>
__global__ __launch_bounds__(256) void gemm_nt(
    const float* __restrict__ A, int lda,
    const float* __restrict__ B, int ldb,
    const float* __restrict__ bias,
    float* __restrict__ C, int ldc,
    float* __restrict__ C2,
    int M, int N, int K)
{
    __shared__ __align__(16) float As[16][68];
    __shared__ __align__(16) float Bs[16][68];

    const int tid = threadIdx.x;
    const int m0 = blockIdx.y * 64;
    const int n0 = blockIdx.x * 64;
    const int sr = tid >> 2;
    const int kc = (tid & 3) * 4;
    const int tx = tid & 15;
    const int ty = tid >> 4;

    float acc[4][4] = {};

    for (int k0 = 0; k0 < K; k0 += 16) {
        float4 a4 = make_float4(0.f, 0.f, 0.f, 0.f);
        int gm = m0 + sr;
        if (gm < M) a4 = *(const float4*)&A[(size_t)gm * lda + k0 + kc];
        As[kc + 0][sr] = a4.x; As[kc + 1][sr] = a4.y;
        As[kc + 2][sr] = a4.z; As[kc + 3][sr] = a4.w;

        float4 b4 = *(const float4*)&B[(size_t)(n0 + sr) * ldb + k0 + kc];
        Bs[kc + 0][sr] = b4.x; Bs[kc + 1][sr] = b4.y;
        Bs[kc + 2][sr] = b4.z; Bs[kc + 3][sr] = b4.w;

        __syncthreads();
        #pragma unroll
        for (int k = 0; k < 16; ++k) {
            float av[4], bv[4];
            *(float4*)av = *(const float4*)&As[k][ty * 4];
            *(float4*)bv = *(const float4*)&Bs[k][tx * 4];
            #pragma unroll
            for (int r = 0; r < 4; ++r)
                #pragma unroll
                for (int c = 0; c < 4; ++c)
                    acc[r][c] = fmaf(av[r], bv[c], acc[r][c]);
        }
        __syncthreads();
    }

    #pragma unroll
    for (int r = 0; r < 4; ++r) {
        int gm = m0 + ty * 4 + r;
        if (gm >= M) continue;
        #pragma unroll
        for (int c = 0; c < 4; ++c) {
            int gn = n0 + tx * 4 + c;
            float v = acc[r][c] + bias[gn];
            if (EPI == 1) v = fmaxf(v, 0.f);
            C[(size_t)gm * ldc + gn] = v;
            if (EPI == 2) C2[(size_t)gm * ldc + gn] = sigmoidf_(v);
        }
    }
}

// ---------------------------------------------------------------------------
// Fused W1 + E1z gemm.  A = z [128,256].
// n0<512: h1 = relu(z@W1^T + b1); n0>=512: Abc = z@E1z^T + c1 (f32)
// ---------------------------------------------------------------------------
__global__ __launch_bounds__(256) void gemm_w1e1(
    const float* __restrict__ z,
    const float* __restrict__ W1, const float* __restrict__ b1,
    const float* __restrict__ E1, const float* __restrict__ c1,
    float* __restrict__ h1, float* __restrict__ Abc)
{
    __shared__ __align__(16) float As[16][68];
    __shared__ __align__(16) float Bs[16][68];

    const int tid = threadIdx.x;
    const int m0 = blockIdx.y * 64;
    const int n0 = blockIdx.x * 64;          // 0..1023
    const bool isE = n0 >= 512;
    const float* Bp = isE ? E1 + (size_t)(n0 - 512) * 384 : W1 + (size_t)n0 * 256;
    const int ldb = isE ? 384 : 256;

    const int sr = tid >> 2;
    const int kc = (tid & 3) * 4;
    const int tx = tid & 15;
    const int ty = tid >> 4;

    float acc[4][4] = {};

    for (int k0 = 0; k0 < 256; k0 += 16) {
        float4 a4 = *(const float4*)&z[(size_t)(m0 + sr) * 256 + k0 + kc];
        As[kc + 0][sr] = a4.x; As[kc + 1][sr] = a4.y;
        As[kc + 2][sr] = a4.z; As[kc + 3][sr] = a4.w;
        float4 b4 = *(const float4*)&Bp[(size_t)sr * ldb + k0 + kc];
        Bs[kc + 0][sr] = b4.x; Bs[kc + 1][sr] = b4.y;
        Bs[kc + 2][sr] = b4.z; Bs[kc + 3][sr] = b4.w;
        __syncthreads();
        #pragma unroll
        for (int k = 0; k < 16; ++k) {
            float av[4], bv[4];
            *(float4*)av = *(const float4*)&As[k][ty * 4];
            *(float4*)bv = *(const float4*)&Bs[k][tx * 4];
            #pragma unroll
            for (int r = 0; r < 4; ++r)
                #pragma unroll
                for (int c = 0; c < 4; ++c)
                    acc[r][c] = fmaf(av[r], bv[c], acc[r][c]);
        }
        __syncthreads();
    }

    #pragma unroll
    for (int r = 0; r < 4; ++r) {
        int gm = m0 + ty * 4 + r;
        #pragma unroll
        for (int c = 0; c < 4; ++c) {
            int gn = n0 + tx * 4 + c;
            if (isE) {
                int gl = gn - 512;
                Abc[(size_t)gm * 512 + gl] = acc[r][c] + c1[gl];
            } else {
                h1[(size_t)gm * 512 + gn] = fmaxf(acc[r][c] + b1[gn], 0.f);
            }
        }
    }
}

// ---------------------------------------------------------------------------
// Fused Ui/Uj gemm.  A = nf [6400,64].
// n0<512:  Uib = bf16(nf@E1i^T + Abc[row/50])     (E1i = E1 cols 256..319)
// n0>=512: Ujb = bf16(nf@E1j^T)                   (E1j = E1 cols 320..383)
// ---------------------------------------------------------------------------
__global__ __launch_bounds__(256) void uiuj_gemm(
    const float* __restrict__ nf,
    const float* __restrict__ E1,
    const float* __restrict__ Abc,
    unsigned short* __restrict__ Uib,
    unsigned short* __restrict__ Ujb)
{
    __shared__ __align__(16) float As[16][68];
    __shared__ __align__(16) float Bs[16][68];

    const int tid = threadIdx.x;
    const int m0 = blockIdx.y * 64;
    const int n0 = blockIdx.x * 64;          // 0..1023
    const bool isJ = n0 >= 512;
    const int nb = n0 & 511;
    const float* Bp = E1 + (size_t)nb * 384 + (isJ ? 320 : 256);

    const int sr = tid >> 2;
    const int kc = (tid & 3) * 4;
    const int tx = tid & 15;
    const int ty = tid >> 4;

    float acc[4][4] = {};

    for (int k0 = 0; k0 < 64; k0 += 16) {
        float4 a4 = *(const float4*)&nf[(size_t)(m0 + sr) * 64 + k0 + kc];
        As[kc + 0][sr] = a4.x; As[kc + 1][sr] = a4.y;
        As[kc + 2][sr] = a4.z; As[kc + 3][sr] = a4.w;
        float4 b4 = *(const float4*)&Bp[(size_t)sr * 384 + k0 + kc];
        Bs[kc + 0][sr] = b4.x; Bs[kc + 1][sr] = b4.y;
        Bs[kc + 2][sr] = b4.z; Bs[kc + 3][sr] = b4.w;
        __syncthreads();
        #pragma unroll
        for (int k = 0; k < 16; ++k) {
            float av[4], bv[4];
            *(float4*)av = *(const float4*)&As[k][ty * 4];
            *(float4*)bv = *(const float4*)&Bs[k][tx * 4];
            #pragma unroll
            for (int r = 0; r < 4; ++r)
                #pragma unroll
                for (int c = 0; c < 4; ++c)
                    acc[r][c] = fmaf(av[r], bv[c], acc[r][c]);
        }
        __syncthreads();
    }

    unsigned short* dst = isJ ? Ujb : Uib;
    #pragma unroll
    for (int r = 0; r < 4; ++r) {
        int gm = m0 + ty * 4 + r;
        int bidx = gm / 50;
        #pragma unroll
        for (int c = 0; c < 4; ++c) {
            int gl = nb + tx * 4 + c;
            float v = acc[r][c];
            if (!isJ) v += Abc[(size_t)bidx * 512 + gl];
            dst[(size_t)gm * 512 + gl] = f2b(v);
        }
    }
}

// ---------------------------------------------------------------------------
// MFMA edge kernel.  Per block: batch b, 128 pairs x 256 g, K=512.
// A-tile (e1) in LDS: row stride 32 shorts, 16B chunks XOR-swizzled by
// (row>>1)&3 -> <=2-way bank access on both ds_write_b128 and ds_read_b128.
// Depth-2 register pipelines (parity sets, fully unrolled) for B-frags (from
// chunk-major E2t) and Ui/Uj build sources.
// ---------------------------------------------------------------------------
__global__ __launch_bounds__(512) void edge_mfma(
    const unsigned short* __restrict__ Ui,   // [B,50,512] bf16 (incl. Abc+c1)
    const unsigned short* __restrict__ Uj,   // [B,50,512] bf16
    const unsigned short* __restrict__ E2t,  // [64 kc][256 g][8] bf16
    const float* __restrict__ c2,
    const float* __restrict__ E3,
    const float* __restrict__ c3p,
    float* __restrict__ outE)                // [B,2450]
{
    __shared__ unsigned short As[2][PTILE * 32];
    __shared__ float c2_s[256], e3_s[256];
    __shared__ int   ii_s[PTILE], jj_s[PTILE];
    __shared__ float red[PTILE][5];

    const int b   = blockIdx.y;
    const int p0  = blockIdx.x * PTILE;
    const int tid = threadIdx.x;
    const int lane = tid & 63;
    const int wid  = tid >> 6;
    const int wr = wid >> 2;
    const int wc = wid & 3;
    const int ln = lane & 15;
    const int hi = lane >> 4;

    if (tid < 256) { c2_s[tid] = c2[tid]; e3_s[tid] = E3[tid]; }
    if (tid < PTILE) {
        int p = p0 + tid;
        int i = 0, j = 0;
        if (p < NPAIR) {
            i = p / 49;
            int kk = p - i * 49;
            j = kk + (kk >= i ? 1 : 0);
        }
        ii_s[tid] = i;
        jj_s[tid] = j;
    }
    __syncthreads();

    const unsigned short* UiB = Ui + (size_t)b * MAXN * HIDDEN;
    const unsigned short* UjB = Uj + (size_t)b * MAXN * HIDDEN;

    // staging role: (row, 16B chunk) of the 128x32 k-step tile
    const int srow = tid >> 2;
    const int sc   = tid & 3;
    const unsigned short* gUi = UiB + (size_t)ii_s[srow] * HIDDEN + sc * 8;
    const unsigned short* gUj = UjB + (size_t)jj_s[srow] * HIDDEN + sc * 8;
    const int swr = srow * 32 + ((sc ^ ((srow >> 1) & 3)) * 8);

    // fragment read addresses
    const int arow = 64 * wr + ln;
    const int q    = hi ^ ((ln >> 1) & 3);
    const int ard  = arow * 32 + q * 8;

    // B source (chunk-major E2t)
    const unsigned short* Bbase = E2t + ((size_t)hi * 256 + 64 * wc + ln) * 8;

    f32x4 acc[4][4] = {};

    // ---- prologue: A(0) into LDS, B(0),B(1) and U(1) into regs
    {
        bf16x8 ui = *(const bf16x8*)gUi;
        bf16x8 uj = *(const bf16x8*)gUj;
        *(u32x4*)&As[0][swr] = build_e1(ui, uj);
    }
    bf16x8 bA[4], bB[4];
    #pragma unroll
    for (int ni = 0; ni < 4; ++ni) {
        bA[ni] = *(const bf16x8*)(Bbase + ni * 128);
        bB[ni] = *(const bf16x8*)(Bbase + 8192 + ni * 128);
    }
    bf16x8 uiA, ujA, uiB, ujB;
    uiB = *(const bf16x8*)(gUi + 32);
    ujB = *(const bf16x8*)(gUj + 32);
    __syncthreads();

    #pragma unroll
    for (int ks = 0; ks < 16; ++ks) {
        bf16x8 af[4];
        const unsigned short* as_rd = &As[ks & 1][ard];
        #pragma unroll
        for (int mi = 0; mi < 4; ++mi)
            af[mi] = *(const bf16x8*)(as_rd + mi * 512);

        #pragma unroll
        for (int ni = 0; ni < 4; ++ni) {
            #pragma unroll
            for (int mi = 0; mi < 4; ++mi)
                acc[mi][ni] = __builtin_amdgcn_mfma_f32_16x16x32_bf16(
                    af[mi], (ks & 1) ? bB[ni] : bA[ni], acc[mi][ni], 0, 0, 0);
            if (ks < 14) {   // prefetch B(ks+2) into the set just freed
                bf16x8 nb = *(const bf16x8*)(Bbase + (size_t)(ks + 2) * 8192 + ni * 128);
                if (ks & 1) bB[ni] = nb; else bA[ni] = nb;
            }
        }

        if (ks < 15) {       // build+store A(ks+1); prefetch U(ks+2)
            *(u32x4*)&As[(ks + 1) & 1][swr] =
                build_e1(((ks + 1) & 1) ? uiB : uiA, ((ks + 1) & 1) ? ujB : ujA);
            if (ks < 14) {
                bf16x8 nui = *(const bf16x8*)(gUi + 32 * (ks + 2));
                bf16x8 nuj = *(const bf16x8*)(gUj + 32 * (ks + 2));
                if (ks & 1) { uiB = nui; ujB = nuj; }
                else        { uiA = nui; ujA = nuj; }
            }
        }
        __syncthreads();
    }

    // ---- epilogue: relu(+c2), dot E3, 16-lane shuffle reduce, cross-wave LDS
    const float c3v = c3p[0];
    #pragma unroll
    for (int mi = 0; mi < 4; ++mi) {
        #pragma unroll
        for (int r = 0; r < 4; ++r) {
            float part = 0.f;
            #pragma unroll
            for (int ni = 0; ni < 4; ++ni) {
                int g = 64 * wc + 16 * ni + ln;
                float v = fmaxf(acc[mi][ni][r] + c2_s[g], 0.f);
                part = fmaf(v, e3_s[g], part);
            }
            part += __shfl_xor(part, 1);
            part += __shfl_xor(part, 2);
            part += __shfl_xor(part, 4);
            part += __shfl_xor(part, 8);
            if (ln == 0) red[64 * wr + 16 * mi + 4 * hi + r][wc] = part;
        }
    }
    __syncthreads();

    if (tid < PTILE) {
        int p = p0 + tid;
        if (p < NPAIR) {
            float s = red[tid][0] + red[tid][1] + red[tid][2] + red[tid][3] + c3v;
            outE[(size_t)b * NPAIR + p] = sigmoidf_(s);
        }
    }
}

// ---------------------------------------------------------------------------
extern "C" void kernel_launch(void* const* d_in, const int* in_sizes, int n_in,
                              void* d_out, int out_size, void* d_ws, size_t ws_size,
                              hipStream_t stream)
{
    const float* z  = (const float*)d_in[0];
    const float* W1 = (const float*)d_in[1];
    const float* b1 = (const float*)d_in[2];
    const float* W2 = (const float*)d_in[3];
    const float* b2 = (const float*)d_in[4];
    const float* W3 = (const float*)d_in[5];
    const float* b3 = (const float*)d_in[6];
    const float* E1 = (const float*)d_in[7];
    const float* c1 = (const float*)d_in[8];
    const float* E2 = (const float*)d_in[9];
    const float* c2 = (const float*)d_in[10];
    const float* E3 = (const float*)d_in[11];
    const float* c3 = (const float*)d_in[12];

    float* out = (float*)d_out;
    float* ws  = (float*)d_ws;

    // workspace layout
    float* h1  = ws;                        // 128*512 f32
    float* h2  = h1 + 65536;                // 128*512 f32
    float* nf  = h2 + 65536;                // 128*3200 f32
    float* Abc = nf + 409600;               // 128*512 f32
    unsigned short* Uib = (unsigned short*)(Abc + 65536);   // 128*50*512 bf16
    unsigned short* Ujb = Uib + (size_t)BATCH * MAXN * 512; // 128*50*512 bf16
    unsigned short* E2t = Ujb + (size_t)BATCH * MAXN * 512; // 64*256*8 bf16

    dim3 blk(256);

    // E2 -> chunk-major bf16
    cvt_e2t<<<dim3(64), blk, 0, stream>>>(E2, E2t);

    // h1 = relu(z@W1^T+b1) ; Abc = z@E1z^T + c1
    gemm_w1e1<<<dim3(16, 2), blk, 0, stream>>>(z, W1, b1, E1, c1, h1, Abc);

    // h2 = relu(h1@W2^T+b2)
    gemm_nt<1><<<dim3(8, 2), blk, 0, stream>>>(
        h1, HIDDEN, W2, HIDDEN, b2, h2, HIDDEN, nullptr, BATCH, HIDDEN, HIDDEN);

    // nf raw -> ws ; sigmoid(nf) -> out
    gemm_nt<2><<<dim3(50, 2), blk, 0, stream>>>(
        h2, HIDDEN, W3, HIDDEN, b3, nf, 3200, out, BATCH, 3200, HIDDEN);

    // Ui' = bf16(nf@E1i^T + Abc) ; Uj = bf16(nf@E1j^T)
    uiuj_gemm<<<dim3(16, 100), blk, 0, stream>>>(nf, E1, Abc, Uib, Ujb);

    // fused edge MLP with MFMA
    edge_mfma<<<dim3(NTILES, BATCH), dim3(512), 0, stream>>>(
        Uib, Ujb, E2t, c2, E3, c3, out + BATCH * MAXN * NFD);
}

// Round 4
// 183.730 us; speedup vs baseline: 5.7818x; 1.1765x over previous
//
#include <hip/hip_runtime.h>
#include <hip/hip_bf16.h>
#include <math.h>

#define LATENT 256
#define HIDDEN 512
#define NFD    64
#define MAXN   50
#define BATCH  128
#define NPAIR  2450   // 50*49
#define PTILE  128
#define NTILES 20     // ceil(2450/128)

typedef __attribute__((ext_vector_type(8))) short bf16x8;
typedef __attribute__((ext_vector_type(4))) float f32x4;
typedef __attribute__((ext_vector_type(4))) unsigned int u32x4;

__device__ __forceinline__ float sigmoidf_(float x) {
    return 1.0f / (1.0f + expf(-x));
}
__device__ __forceinline__ unsigned short f2b(float f) {   // fp32 -> bf16 RNE
    unsigned u = __builtin_bit_cast(unsigned, f);
    u += 0x7FFFu + ((u >> 16) & 1u);
    return (unsigned short)(u >> 16);
}
__device__ __forceinline__ float b2f(short s) {
    unsigned u = ((unsigned)(unsigned short)s) << 16;
    return __builtin_bit_cast(float, u);
}
__device__ __forceinline__ unsigned cvt_pk_bf16(float lo, float hi) {
    unsigned r;
    asm("v_cvt_pk_bf16_f32 %0, %1, %2" : "=v"(r) : "v"(lo), "v"(hi));
    return r;
}
// e1 8-elem build: relu(b2f(ui)+b2f(uj)) packed to 4x u32 (8 bf16)
__device__ __forceinline__ u32x4 build_e1(bf16x8 ui, bf16x8 uj) {
    u32x4 o;
    #pragma unroll
    for (int t = 0; t < 4; ++t) {
        float lo = fmaxf(b2f(ui[2 * t])     + b2f(uj[2 * t]),     0.f);
        float hh = fmaxf(b2f(ui[2 * t + 1]) + b2f(uj[2 * t + 1]), 0.f);
        o[t] = cvt_pk_bf16(lo, hh);
    }
    return o;
}
// async global(16B/lane) -> LDS (wave-uniform base + lane*16)
__device__ __forceinline__ void gll16(const void* g, void* l) {
    __builtin_amdgcn_global_load_lds(
        (const __attribute__((address_space(1))) void*)g,
        (__attribute__((address_space(3))) void*)l, 16, 0, 0);
}

// ---------------------------------------------------------------------------
// Prologue A (two roles by blockIdx.x):
//  x < 16 : h1 = relu(z@W1^T+b1)  (n0<512)  /  Abc = z@E1z^T+c1 (n0>=512)
//  x >= 16: E2 [256,512] f32 -> E2t chunk-major bf16 (64 blocks)
// ---------------------------------------------------------------------------
__global__ __launch_bounds__(256) void prologue_a(
    const float* __restrict__ z,
    const float* __restrict__ W1, const float* __restrict__ b1,
    const float* __restrict__ E1, const float* __restrict__ c1,
    const float* __restrict__ E2, unsigned short* __restrict__ E2t,
    float* __restrict__ h1, float* __restrict__ Abc)
{
    const int tid = threadIdx.x;

    if (blockIdx.x >= 16) {   // E2 -> chunk-major bf16
        int idx = ((blockIdx.x - 16) + blockIdx.y * 32) * 256 + tid;  // 16384
        int g  = idx & 255;
        int kc = idx >> 8;
        float4 a = *(const float4*)&E2[(size_t)g * 512 + kc * 8];
        float4 b = *(const float4*)&E2[(size_t)g * 512 + kc * 8 + 4];
        u32x4 o;
        o[0] = (unsigned)f2b(a.x) | ((unsigned)f2b(a.y) << 16);
        o[1] = (unsigned)f2b(a.z) | ((unsigned)f2b(a.w) << 16);
        o[2] = (unsigned)f2b(b.x) | ((unsigned)f2b(b.y) << 16);
        o[3] = (unsigned)f2b(b.z) | ((unsigned)f2b(b.w) << 16);
        *(u32x4*)(E2t + (size_t)idx * 8) = o;
        return;
    }

    __shared__ __align__(16) float As[16][68];
    __shared__ __align__(16) float Bs[16][68];

    const int m0 = blockIdx.y * 64;
    const int n0 = blockIdx.x * 64;          // 0..1023
    const bool isE = n0 >= 512;
    const float* Bp = isE ? E1 + (size_t)(n0 - 512) * 384 : W1 + (size_t)n0 * 256;
    const int ldb = isE ? 384 : 256;

    const int sr = tid >> 2;
    const int kc = (tid & 3) * 4;
    const int tx = tid & 15;
    const int ty = tid >> 4;

    float acc[4][4] = {};

    for (int k0 = 0; k0 < 256; k0 += 16) {
        float4 a4 = *(const float4*)&z[(size_t)(m0 + sr) * 256 + k0 + kc];
        As[kc + 0][sr] = a4.x; As[kc + 1][sr] = a4.y;
        As[kc + 2][sr] = a4.z; As[kc + 3][sr] = a4.w;
        float4 b4 = *(const float4*)&Bp[(size_t)sr * ldb + k0 + kc];
        Bs[kc + 0][sr] = b4.x; Bs[kc + 1][sr] = b4.y;
        Bs[kc + 2][sr] = b4.z; Bs[kc + 3][sr] = b4.w;
        __syncthreads();
        #pragma unroll
        for (int k = 0; k < 16; ++k) {
            float av[4], bv[4];
            *(float4*)av = *(const float4*)&As[k][ty * 4];
            *(float4*)bv = *(const float4*)&Bs[k][tx * 4];
            #pragma unroll
            for (int r = 0; r < 4; ++r)
                #pragma unroll
                for (int c = 0; c < 4; ++c)
                    acc[r][c] = fmaf(av[r], bv[c], acc[r][c]);
        }
        __syncthreads();
    }

    #pragma unroll
    for (int r = 0; r < 4; ++r) {
        int gm = m0 + ty * 4 + r;
        #pragma unroll
        for (int c = 0; c < 4; ++c) {
            int gn = n0 + tx * 4 + c;
            if (isE) {
                int gl = gn - 512;
                Abc[(size_t)gm * 512 + gl] = acc[r][c] + c1[gl];
            } else {
                h1[(size_t)gm * 512 + gn] = fmaxf(acc[r][c] + b1[gn], 0.f);
            }
        }
    }
}

// ---------------------------------------------------------------------------
// fp32 NT gemm, tile 64x64, 256 thr, 4x4/thread.
// EPI: 1 relu->C ; 2 raw->C + sigmoid->C2
// ---------------------------------------------------------------------------
template <int EPI>
__global__ __launch_bounds__(256) void gemm_nt(
    const float* __restrict__ A, int lda,
    const float* __restrict__ B, int ldb,
    const float* __restrict__ bias,
    float* __restrict__ C, int ldc,
    float* __restrict__ C2,
    int M, int N, int K)
{
    __shared__ __align__(16) float As[16][68];
    __shared__ __align__(16) float Bs[16][68];

    const int tid = threadIdx.x;
    const int m0 = blockIdx.y * 64;
    const int n0 = blockIdx.x * 64;
    const int sr = tid >> 2;
    const int kc = (tid & 3) * 4;
    const int tx = tid & 15;
    const int ty = tid >> 4;

    float acc[4][4] = {};

    for (int k0 = 0; k0 < K; k0 += 16) {
        float4 a4 = make_float4(0.f, 0.f, 0.f, 0.f);
        int gm = m0 + sr;
        if (gm < M) a4 = *(const float4*)&A[(size_t)gm * lda + k0 + kc];
        As[kc + 0][sr] = a4.x; As[kc + 1][sr] = a4.y;
        As[kc + 2][sr] = a4.z; As[kc + 3][sr] = a4.w;

        float4 b4 = *(const float4*)&B[(size_t)(n0 + sr) * ldb + k0 + kc];
        Bs[kc + 0][sr] = b4.x; Bs[kc + 1][sr] = b4.y;
        Bs[kc + 2][sr] = b4.z; Bs[kc + 3][sr] = b4.w;

        __syncthreads();
        #pragma unroll
        for (int k = 0; k < 16; ++k) {
            float av[4], bv[4];
            *(float4*)av = *(const float4*)&As[k][ty * 4];
            *(float4*)bv = *(const float4*)&Bs[k][tx * 4];
            #pragma unroll
            for (int r = 0; r < 4; ++r)
                #pragma unroll
                for (int c = 0; c < 4; ++c)
                    acc[r][c] = fmaf(av[r], bv[c], acc[r][c]);
        }
        __syncthreads();
    }

    #pragma unroll
    for (int r = 0; r < 4; ++r) {
        int gm = m0 + ty * 4 + r;
        if (gm >= M) continue;
        #pragma unroll
        for (int c = 0; c < 4; ++c) {
            int gn = n0 + tx * 4 + c;
            float v = acc[r][c] + bias[gn];
            if (EPI == 1) v = fmaxf(v, 0.f);
            C[(size_t)gm * ldc + gn] = v;
            if (EPI == 2) C2[(size_t)gm * ldc + gn] = sigmoidf_(v);
        }
    }
}

// ---------------------------------------------------------------------------
// Fused Ui/Uj gemm.  A = nf [6400,64].
// n0<512:  Uib = bf16(nf@E1i^T + Abc[row/50]) ; n0>=512: Ujb = bf16(nf@E1j^T)
// ---------------------------------------------------------------------------
__global__ __launch_bounds__(256) void uiuj_gemm(
    const float* __restrict__ nf,
    const float* __restrict__ E1,
    const float* __restrict__ Abc,
    unsigned short* __restrict__ Uib,
    unsigned short* __restrict__ Ujb)
{
    __shared__ __align__(16) float As[16][68];
    __shared__ __align__(16) float Bs[16][68];

    const int tid = threadIdx.x;
    const int m0 = blockIdx.y * 64;
    const int n0 = blockIdx.x * 64;          // 0..1023
    const bool isJ = n0 >= 512;
    const int nb = n0 & 511;
    const float* Bp = E1 + (size_t)nb * 384 + (isJ ? 320 : 256);

    const int sr = tid >> 2;
    const int kc = (tid & 3) * 4;
    const int tx = tid & 15;
    const int ty = tid >> 4;

    float acc[4][4] = {};

    for (int k0 = 0; k0 < 64; k0 += 16) {
        float4 a4 = *(const float4*)&nf[(size_t)(m0 + sr) * 64 + k0 + kc];
        As[kc + 0][sr] = a4.x; As[kc + 1][sr] = a4.y;
        As[kc + 2][sr] = a4.z; As[kc + 3][sr] = a4.w;
        float4 b4 = *(const float4*)&Bp[(size_t)sr * 384 + k0 + kc];
        Bs[kc + 0][sr] = b4.x; Bs[kc + 1][sr] = b4.y;
        Bs[kc + 2][sr] = b4.z; Bs[kc + 3][sr] = b4.w;
        __syncthreads();
        #pragma unroll
        for (int k = 0; k < 16; ++k) {
            float av[4], bv[4];
            *(float4*)av = *(const float4*)&As[k][ty * 4];
            *(float4*)bv = *(const float4*)&Bs[k][tx * 4];
            #pragma unroll
            for (int r = 0; r < 4; ++r)
                #pragma unroll
                for (int c = 0; c < 4; ++c)
                    acc[r][c] = fmaf(av[r], bv[c], acc[r][c]);
        }
        __syncthreads();
    }

    unsigned short* dst = isJ ? Ujb : Uib;
    #pragma unroll
    for (int r = 0; r < 4; ++r) {
        int gm = m0 + ty * 4 + r;
        int bidx = gm / 50;
        #pragma unroll
        for (int c = 0; c < 4; ++c) {
            int gl = nb + tx * 4 + c;
            float v = acc[r][c];
            if (!isJ) v += Abc[(size_t)bidx * 512 + gl];
            dst[(size_t)gm * 512 + gl] = f2b(v);
        }
    }
}

// ---------------------------------------------------------------------------
// MFMA edge kernel v3.  Per block: batch b, 128 pairs x 256 g, K=512.
//  - A (e1, built on the fly): XOR-swizzled LDS, double-buffered
//  - B (E2t): global_load_lds -> linear LDS, double-buffered (16KB/k-step)
//  - __launch_bounds__(512,4): VGPR<=128 -> 2 blocks/CU co-resident
// ---------------------------------------------------------------------------
__global__ __launch_bounds__(512, 4) void edge_mfma(
    const unsigned short* __restrict__ Ui,   // [B,50,512] bf16 (incl. Abc+c1)
    const unsigned short* __restrict__ Uj,   // [B,50,512] bf16
    const unsigned short* __restrict__ E2t,  // [64 kc][256 g][8] bf16
    const float* __restrict__ c2,
    const float* __restrict__ E3,
    const float* __restrict__ c3p,
    float* __restrict__ outE)                // [B,2450]
{
    __shared__ unsigned short As[2][PTILE * 32];   // 16KB, swizzled
    __shared__ unsigned short Bs[2][4 * 256 * 8];  // 32KB, linear chunk-major
    __shared__ float c2_s[256], e3_s[256];
    __shared__ int   ii_s[PTILE], jj_s[PTILE];
    __shared__ float red[PTILE][5];

    const int b   = blockIdx.y;
    const int p0  = blockIdx.x * PTILE;
    const int tid = threadIdx.x;
    const int lane = tid & 63;
    const int wid  = tid >> 6;
    const int wr = wid >> 2;
    const int wc = wid & 3;
    const int ln = lane & 15;
    const int hi = lane >> 4;

    if (tid < 256) { c2_s[tid] = c2[tid]; e3_s[tid] = E3[tid]; }
    if (tid < PTILE) {
        int p = p0 + tid;
        int i = 0, j = 0;
        if (p < NPAIR) {
            i = p / 49;
            int kk = p - i * 49;
            j = kk + (kk >= i ? 1 : 0);
        }
        ii_s[tid] = i;
        jj_s[tid] = j;
    }
    __syncthreads();

    const unsigned short* UiB = Ui + (size_t)b * MAXN * HIDDEN;
    const unsigned short* UjB = Uj + (size_t)b * MAXN * HIDDEN;

    // A staging role: (row, 16B chunk) of the 128x32 k-step tile
    const int srow = tid >> 2;
    const int sc   = tid & 3;
    const unsigned short* gUi = UiB + (size_t)ii_s[srow] * HIDDEN + sc * 8;
    const unsigned short* gUj = UjB + (size_t)jj_s[srow] * HIDDEN + sc * 8;
    const int swr = srow * 32 + ((sc ^ ((srow >> 1) & 3)) * 8);

    // A fragment read address (swizzled)
    const int arow = 64 * wr + ln;
    const int q    = hi ^ ((ln >> 1) & 3);
    const int ard  = arow * 32 + q * 8;

    // B: per-wave gll source / LDS fragment read address
    const unsigned short* gB  = E2t + (wid * 2) * 512 + lane * 8;
    const int bdst = (wid * 2) * 512;                 // shorts, uniform/wave
    const int brd  = hi * 2048 + (64 * wc + ln) * 8;  // + ni*128

    f32x4 acc[4][4] = {};

    // ---- prologue: A(0) build->LDS, B(0) gll->LDS, U(1) regs
    {
        bf16x8 ui = *(const bf16x8*)gUi;
        bf16x8 uj = *(const bf16x8*)gUj;
        *(u32x4*)&As[0][swr] = build_e1(ui, uj);
    }
    gll16(gB,       &Bs[0][bdst]);
    gll16(gB + 512, &Bs[0][bdst + 512]);
    bf16x8 uiN = *(const bf16x8*)(gUi + 32);
    bf16x8 ujN = *(const bf16x8*)(gUj + 32);
    __syncthreads();

    #pragma unroll
    for (int ks = 0; ks < 16; ++ks) {
        const int cur = ks & 1;
        if (ks < 15) {
            // issue B(ks+1) -> Bs[!cur]  (drained by the barrier below)
            const unsigned short* src = gB + (ks + 1) * 8192;
            gll16(src,       &Bs[cur ^ 1][bdst]);
            gll16(src + 512, &Bs[cur ^ 1][bdst + 512]);
            // build + store A(ks+1)
            *(u32x4*)&As[cur ^ 1][swr] = build_e1(uiN, ujN);
        }
        if (ks < 14) {
            uiN = *(const bf16x8*)(gUi + 32 * (ks + 2));
            ujN = *(const bf16x8*)(gUj + 32 * (ks + 2));
        }
        bf16x8 af[4], bf[4];
        #pragma unroll
        for (int mi = 0; mi < 4; ++mi)
            af[mi] = *(const bf16x8*)&As[cur][ard + mi * 512];
        #pragma unroll
        for (int ni = 0; ni < 4; ++ni)
            bf[ni] = *(const bf16x8*)&Bs[cur][brd + ni * 128];
        #pragma unroll
        for (int ni = 0; ni < 4; ++ni)
            #pragma unroll
            for (int mi = 0; mi < 4; ++mi)
                acc[mi][ni] = __builtin_amdgcn_mfma_f32_16x16x32_bf16(
                    af[mi], bf[ni], acc[mi][ni], 0, 0, 0);
        __syncthreads();
    }

    // ---- epilogue: relu(+c2), dot E3, 16-lane shuffle reduce, cross-wave LDS
    const float c3v = c3p[0];
    #pragma unroll
    for (int mi = 0; mi < 4; ++mi) {
        #pragma unroll
        for (int r = 0; r < 4; ++r) {
            float part = 0.f;
            #pragma unroll
            for (int ni = 0; ni < 4; ++ni) {
                int g = 64 * wc + 16 * ni + ln;
                float v = fmaxf(acc[mi][ni][r] + c2_s[g], 0.f);
                part = fmaf(v, e3_s[g], part);
            }
            part += __shfl_xor(part, 1);
            part += __shfl_xor(part, 2);
            part += __shfl_xor(part, 4);
            part += __shfl_xor(part, 8);
            if (ln == 0) red[64 * wr + 16 * mi + 4 * hi + r][wc] = part;
        }
    }
    __syncthreads();

    if (tid < PTILE) {
        int p = p0 + tid;
        if (p < NPAIR) {
            float s = red[tid][0] + red[tid][1] + red[tid][2] + red[tid][3] + c3v;
            outE[(size_t)b * NPAIR + p] = sigmoidf_(s);
        }
    }
}

// ---------------------------------------------------------------------------
extern "C" void kernel_launch(void* const* d_in, const int* in_sizes, int n_in,
                              void* d_out, int out_size, void* d_ws, size_t ws_size,
                              hipStream_t stream)
{
    const float* z  = (const float*)d_in[0];
    const float* W1 = (const float*)d_in[1];
    const float* b1 = (const float*)d_in[2];
    const float* W2 = (const float*)d_in[3];
    const float* b2 = (const float*)d_in[4];
    const float* W3 = (const float*)d_in[5];
    const float* b3 = (const float*)d_in[6];
    const float* E1 = (const float*)d_in[7];
    const float* c1 = (const float*)d_in[8];
    const float* E2 = (const float*)d_in[9];
    const float* c2 = (const float*)d_in[10];
    const float* E3 = (const float*)d_in[11];
    const float* c3 = (const float*)d_in[12];

    float* out = (float*)d_out;
    float* ws  = (float*)d_ws;

    // workspace layout
    float* h1  = ws;                        // 128*512 f32
    float* h2  = h1 + 65536;                // 128*512 f32
    float* nf  = h2 + 65536;                // 128*3200 f32
    float* Abc = nf + 409600;               // 128*512 f32
    unsigned short* Uib = (unsigned short*)(Abc + 65536);   // 128*50*512 bf16
    unsigned short* Ujb = Uib + (size_t)BATCH * MAXN * 512; // 128*50*512 bf16
    unsigned short* E2t = Ujb + (size_t)BATCH * MAXN * 512; // 64*256*8 bf16

    dim3 blk(256);

    // h1, Abc, E2t
    prologue_a<<<dim3(48, 2), blk, 0, stream>>>(z, W1, b1, E1, c1, E2, E2t, h1, Abc);

    // h2 = relu(h1@W2^T+b2)
    gemm_nt<1><<<dim3(8, 2), blk, 0, stream>>>(
        h1, HIDDEN, W2, HIDDEN, b2, h2, HIDDEN, nullptr, BATCH, HIDDEN, HIDDEN);

    // nf raw -> ws ; sigmoid(nf) -> out
    gemm_nt<2><<<dim3(50, 2), blk, 0, stream>>>(
        h2, HIDDEN, W3, HIDDEN, b3, nf, 3200, out, BATCH, 3200, HIDDEN);

    // Ui' = bf16(nf@E1i^T + Abc) ; Uj = bf16(nf@E1j^T)
    uiuj_gemm<<<dim3(16, 100), blk, 0, stream>>>(nf, E1, Abc, Uib, Ujb);

    // fused edge MLP with MFMA
    edge_mfma<<<dim3(NTILES, BATCH), dim3(512), 0, stream>>>(
        Uib, Ujb, E2t, c2, E3, c3, out + BATCH * MAXN * NFD);
}

// Round 5
// 166.508 us; speedup vs baseline: 6.3799x; 1.1034x over previous
//
#include <hip/hip_runtime.h>
#include <hip/hip_bf16.h>
#include <math.h>

#define LATENT 256
#define HIDDEN 512
#define NFD    64
#define MAXN   50
#define BATCH  128
#define NPAIR  2450   // 50*49
#define PTILE  128
#define NTILES 20     // ceil(2450/128)

typedef __attribute__((ext_vector_type(8))) short bf16x8;
typedef __attribute__((ext_vector_type(4))) float f32x4;
typedef __attribute__((ext_vector_type(4))) unsigned int u32x4;

__device__ __forceinline__ float sigmoidf_(float x) {
    return 1.0f / (1.0f + expf(-x));
}
__device__ __forceinline__ unsigned short f2b(float f) {   // fp32 -> bf16 RNE
    unsigned u = __builtin_bit_cast(unsigned, f);
    u += 0x7FFFu + ((u >> 16) & 1u);
    return (unsigned short)(u >> 16);
}
__device__ __forceinline__ float b2f(short s) {
    unsigned u = ((unsigned)(unsigned short)s) << 16;
    return __builtin_bit_cast(float, u);
}
__device__ __forceinline__ unsigned cvt_pk_bf16(float lo, float hi) {
    unsigned r;
    asm("v_cvt_pk_bf16_f32 %0, %1, %2" : "=v"(r) : "v"(lo), "v"(hi));
    return r;
}
// e1 8-elem build: relu(b2f(ui)+b2f(uj)) packed to 4x u32 (8 bf16)
__device__ __forceinline__ u32x4 build_e1(bf16x8 ui, bf16x8 uj) {
    u32x4 o;
    #pragma unroll
    for (int t = 0; t < 4; ++t) {
        float lo = fmaxf(b2f(ui[2 * t])     + b2f(uj[2 * t]),     0.f);
        float hh = fmaxf(b2f(ui[2 * t + 1]) + b2f(uj[2 * t + 1]), 0.f);
        o[t] = cvt_pk_bf16(lo, hh);
    }
    return o;
}
// async global(16B/lane) -> LDS (wave-uniform base + lane*16)
__device__ __forceinline__ void gll16(const void* g, void* l) {
    __builtin_amdgcn_global_load_lds(
        (const __attribute__((address_space(1))) void*)g,
        (__attribute__((address_space(3))) void*)l, 16, 0, 0);
}

// ---------------------------------------------------------------------------
// Prologue A (two roles by blockIdx.x):
//  x < 16 : h1 = relu(z@W1^T+b1)  (n0<512)  /  Abc = z@E1z^T+c1 (n0>=512)
//  x >= 16: E2 [256,512] f32 -> E2t chunk-major bf16
// ---------------------------------------------------------------------------
__global__ __launch_bounds__(256) void prologue_a(
    const float* __restrict__ z,
    const float* __restrict__ W1, const float* __restrict__ b1,
    const float* __restrict__ E1, const float* __restrict__ c1,
    const float* __restrict__ E2, unsigned short* __restrict__ E2t,
    float* __restrict__ h1, float* __restrict__ Abc)
{
    const int tid = threadIdx.x;

    if (blockIdx.x >= 16) {   // E2 -> chunk-major bf16
        int idx = ((blockIdx.x - 16) + blockIdx.y * 32) * 256 + tid;  // 16384
        int g  = idx & 255;
        int kc = idx >> 8;
        float4 a = *(const float4*)&E2[(size_t)g * 512 + kc * 8];
        float4 b = *(const float4*)&E2[(size_t)g * 512 + kc * 8 + 4];
        u32x4 o;
        o[0] = (unsigned)f2b(a.x) | ((unsigned)f2b(a.y) << 16);
        o[1] = (unsigned)f2b(a.z) | ((unsigned)f2b(a.w) << 16);
        o[2] = (unsigned)f2b(b.x) | ((unsigned)f2b(b.y) << 16);
        o[3] = (unsigned)f2b(b.z) | ((unsigned)f2b(b.w) << 16);
        *(u32x4*)(E2t + (size_t)idx * 8) = o;
        return;
    }

    __shared__ __align__(16) float As[16][68];
    __shared__ __align__(16) float Bs[16][68];

    const int m0 = blockIdx.y * 64;
    const int n0 = blockIdx.x * 64;          // 0..1023
    const bool isE = n0 >= 512;
    const float* Bp = isE ? E1 + (size_t)(n0 - 512) * 384 : W1 + (size_t)n0 * 256;
    const int ldb = isE ? 384 : 256;

    const int sr = tid >> 2;
    const int kc = (tid & 3) * 4;
    const int tx = tid & 15;
    const int ty = tid >> 4;

    float acc[4][4] = {};

    for (int k0 = 0; k0 < 256; k0 += 16) {
        float4 a4 = *(const float4*)&z[(size_t)(m0 + sr) * 256 + k0 + kc];
        As[kc + 0][sr] = a4.x; As[kc + 1][sr] = a4.y;
        As[kc + 2][sr] = a4.z; As[kc + 3][sr] = a4.w;
        float4 b4 = *(const float4*)&Bp[(size_t)sr * ldb + k0 + kc];
        Bs[kc + 0][sr] = b4.x; Bs[kc + 1][sr] = b4.y;
        Bs[kc + 2][sr] = b4.z; Bs[kc + 3][sr] = b4.w;
        __syncthreads();
        #pragma unroll
        for (int k = 0; k < 16; ++k) {
            float av[4], bv[4];
            *(float4*)av = *(const float4*)&As[k][ty * 4];
            *(float4*)bv = *(const float4*)&Bs[k][tx * 4];
            #pragma unroll
            for (int r = 0; r < 4; ++r)
                #pragma unroll
                for (int c = 0; c < 4; ++c)
                    acc[r][c] = fmaf(av[r], bv[c], acc[r][c]);
        }
        __syncthreads();
    }

    #pragma unroll
    for (int r = 0; r < 4; ++r) {
        int gm = m0 + ty * 4 + r;
        #pragma unroll
        for (int c = 0; c < 4; ++c) {
            int gn = n0 + tx * 4 + c;
            if (isE) {
                int gl = gn - 512;
                Abc[(size_t)gm * 512 + gl] = acc[r][c] + c1[gl];
            } else {
                h1[(size_t)gm * 512 + gn] = fmaxf(acc[r][c] + b1[gn], 0.f);
            }
        }
    }
}

// ---------------------------------------------------------------------------
// fp32 NT gemm, tile 32x64, 256 thr, 2x4/thread. More blocks for small M.
// EPI: 1 relu->C ; 2 raw->C + sigmoid->C2.  M%32==0, N%64==0, K%16==0.
// ---------------------------------------------------------------------------
template <int EPI>
__global__ __launch_bounds__(256) void gemm_nt32(
    const float* __restrict__ A, int lda,
    const float* __restrict__ B, int ldb,
    const float* __restrict__ bias,
    float* __restrict__ C, int ldc,
    float* __restrict__ C2,
    int K)
{
    __shared__ __align__(16) float As[16][34];
    __shared__ __align__(16) float Bs[16][68];

    const int tid = threadIdx.x;
    const int m0 = blockIdx.y * 32;
    const int n0 = blockIdx.x * 64;
    const int sra = tid >> 3;        // 0..31
    const int kca = (tid & 7) * 2;
    const int srb = tid >> 2;        // 0..63
    const int kcb = (tid & 3) * 4;
    const int tx = tid & 15;
    const int ty = tid >> 4;         // 0..15

    float acc[2][4] = {};

    for (int k0 = 0; k0 < K; k0 += 16) {
        float2 a2 = *(const float2*)&A[(size_t)(m0 + sra) * lda + k0 + kca];
        As[kca][sra] = a2.x; As[kca + 1][sra] = a2.y;
        float4 b4 = *(const float4*)&B[(size_t)(n0 + srb) * ldb + k0 + kcb];
        Bs[kcb + 0][srb] = b4.x; Bs[kcb + 1][srb] = b4.y;
        Bs[kcb + 2][srb] = b4.z; Bs[kcb + 3][srb] = b4.w;
        __syncthreads();
        #pragma unroll
        for (int k = 0; k < 16; ++k) {
            float av[2], bv[4];
            av[0] = As[k][ty * 2]; av[1] = As[k][ty * 2 + 1];
            *(float4*)bv = *(const float4*)&Bs[k][tx * 4];
            #pragma unroll
            for (int r = 0; r < 2; ++r)
                #pragma unroll
                for (int c = 0; c < 4; ++c)
                    acc[r][c] = fmaf(av[r], bv[c], acc[r][c]);
        }
        __syncthreads();
    }

    #pragma unroll
    for (int r = 0; r < 2; ++r) {
        int gm = m0 + ty * 2 + r;
        #pragma unroll
        for (int c = 0; c < 4; ++c) {
            int gn = n0 + tx * 4 + c;
            float v = acc[r][c] + bias[gn];
            if (EPI == 1) v = fmaxf(v, 0.f);
            C[(size_t)gm * ldc + gn] = v;
            if (EPI == 2) C2[(size_t)gm * ldc + gn] = sigmoidf_(v);
        }
    }
}

// ---------------------------------------------------------------------------
// Fused Ui/Uj gemm.  A = nf [6400,64].
// n0<512:  Uib = bf16(nf@E1i^T + Abc[row/50]) ; n0>=512: Ujb = bf16(nf@E1j^T)
// ---------------------------------------------------------------------------
__global__ __launch_bounds__(256) void uiuj_gemm(
    const float* __restrict__ nf,
    const float* __restrict__ E1,
    const float* __restrict__ Abc,
    unsigned short* __restrict__ Uib,
    unsigned short* __restrict__ Ujb)
{
    __shared__ __align__(16) float As[16][68];
    __shared__ __align__(16) float Bs[16][68];

    const int tid = threadIdx.x;
    const int m0 = blockIdx.y * 64;
    const int n0 = blockIdx.x * 64;          // 0..1023
    const bool isJ = n0 >= 512;
    const int nb = n0 & 511;
    const float* Bp = E1 + (size_t)nb * 384 + (isJ ? 320 : 256);

    const int sr = tid >> 2;
    const int kc = (tid & 3) * 4;
    const int tx = tid & 15;
    const int ty = tid >> 4;

    float acc[4][4] = {};

    for (int k0 = 0; k0 < 64; k0 += 16) {
        float4 a4 = *(const float4*)&nf[(size_t)(m0 + sr) * 64 + k0 + kc];
        As[kc + 0][sr] = a4.x; As[kc + 1][sr] = a4.y;
        As[kc + 2][sr] = a4.z; As[kc + 3][sr] = a4.w;
        float4 b4 = *(const float4*)&Bp[(size_t)sr * 384 + k0 + kc];
        Bs[kc + 0][sr] = b4.x; Bs[kc + 1][sr] = b4.y;
        Bs[kc + 2][sr] = b4.z; Bs[kc + 3][sr] = b4.w;
        __syncthreads();
        #pragma unroll
        for (int k = 0; k < 16; ++k) {
            float av[4], bv[4];
            *(float4*)av = *(const float4*)&As[k][ty * 4];
            *(float4*)bv = *(const float4*)&Bs[k][tx * 4];
            #pragma unroll
            for (int r = 0; r < 4; ++r)
                #pragma unroll
                for (int c = 0; c < 4; ++c)
                    acc[r][c] = fmaf(av[r], bv[c], acc[r][c]);
        }
        __syncthreads();
    }

    unsigned short* dst = isJ ? Ujb : Uib;
    #pragma unroll
    for (int r = 0; r < 4; ++r) {
        int gm = m0 + ty * 4 + r;
        int bidx = gm / 50;
        #pragma unroll
        for (int c = 0; c < 4; ++c) {
            int gl = nb + tx * 4 + c;
            float v = acc[r][c];
            if (!isJ) v += Abc[(size_t)bidx * 512 + gl];
            dst[(size_t)gm * 512 + gl] = f2b(v);
        }
    }
}

// ---------------------------------------------------------------------------
// MFMA edge kernel v4: counted-vmcnt pipeline (T3/T4) + setprio (T5).
//  - A (e1): XOR-swizzled LDS, double-buffered; U regs prefetched 2 deep
//  - B (E2t): gll -> triple-buffered LDS, prefetch distance 2
//  - barrier = fused asm "s_waitcnt vmcnt(4) lgkmcnt(0); s_barrier":
//    the 4 newest vmem ops (gll B(ks+2) x2 + U(ks+2) x2) stay in flight;
//    B(ks+1), issued a full iteration earlier, is drained stall-free.
// ---------------------------------------------------------------------------
__global__ __launch_bounds__(512, 4) void edge_mfma(
    const unsigned short* __restrict__ Ui,   // [B,50,512] bf16 (incl. Abc+c1)
    const unsigned short* __restrict__ Uj,   // [B,50,512] bf16
    const unsigned short* __restrict__ E2t,  // [64 kc][256 g][8] bf16
    const float* __restrict__ c2,
    const float* __restrict__ E3,
    const float* __restrict__ c3p,
    float* __restrict__ outE)                // [B,2450]
{
    __shared__ unsigned short As[2][PTILE * 32];   // 16KB, swizzled
    __shared__ unsigned short Bs[3][4 * 256 * 8];  // 48KB, linear chunk-major
    __shared__ float c2_s[256], e3_s[256];
    __shared__ int   ii_s[PTILE], jj_s[PTILE];
    __shared__ float red[PTILE][5];

    const int b   = blockIdx.y;
    const int p0  = blockIdx.x * PTILE;
    const int tid = threadIdx.x;
    const int lane = tid & 63;
    const int wid  = tid >> 6;
    const int wr = wid >> 2;
    const int wc = wid & 3;
    const int ln = lane & 15;
    const int hi = lane >> 4;

    if (tid < 256) { c2_s[tid] = c2[tid]; e3_s[tid] = E3[tid]; }
    if (tid < PTILE) {
        int p = p0 + tid;
        int i = 0, j = 0;
        if (p < NPAIR) {
            i = p / 49;
            int kk = p - i * 49;
            j = kk + (kk >= i ? 1 : 0);
        }
        ii_s[tid] = i;
        jj_s[tid] = j;
    }
    __syncthreads();

    const unsigned short* UiB = Ui + (size_t)b * MAXN * HIDDEN;
    const unsigned short* UjB = Uj + (size_t)b * MAXN * HIDDEN;

    // A staging role: (row, 16B chunk) of the 128x32 k-step tile
    const int srow = tid >> 2;
    const int sc   = tid & 3;
    const unsigned short* gUi = UiB + (size_t)ii_s[srow] * HIDDEN + sc * 8;
    const unsigned short* gUj = UjB + (size_t)jj_s[srow] * HIDDEN + sc * 8;
    const int swr = srow * 32 + ((sc ^ ((srow >> 1) & 3)) * 8);

    // A fragment read address (swizzled)
    const int arow = 64 * wr + ln;
    const int q    = hi ^ ((ln >> 1) & 3);
    const int ard  = arow * 32 + q * 8;

    // B: per-wave gll source / LDS fragment read address
    const unsigned short* gB  = E2t + (wid * 2) * 512 + lane * 8;
    const int bdst = (wid * 2) * 512;                 // shorts, uniform/wave
    const int brd  = hi * 2048 + (64 * wc + ln) * 8;  // + ni*128

    f32x4 acc[4][4] = {};

    // ---- prologue: A(0) build->LDS; gll B(0)->Bs[0], B(1)->Bs[1]; U(1) regs
    {
        bf16x8 ui = *(const bf16x8*)gUi;
        bf16x8 uj = *(const bf16x8*)gUj;
        *(u32x4*)&As[0][swr] = build_e1(ui, uj);
    }
    gll16(gB,        &Bs[0][bdst]);
    gll16(gB + 512,  &Bs[0][bdst + 512]);
    gll16(gB + 8192, &Bs[1][bdst]);
    gll16(gB + 8704, &Bs[1][bdst + 512]);
    bf16x8 uiN = *(const bf16x8*)(gUi + 32);
    bf16x8 ujN = *(const bf16x8*)(gUj + 32);
    // drain B(0) (oldest); keep B(1)+U(1) (4 newest) in flight
    asm volatile("s_waitcnt vmcnt(4) lgkmcnt(0)\n\ts_barrier" ::: "memory");

    #pragma unroll
    for (int ks = 0; ks < 16; ++ks) {
        const int ab = ks & 1;        // A buffer
        const int bb = ks % 3;        // B buffer
        // issue B(ks+2) -> Bs[(ks+2)%3] (that buffer was last read at ks-1)
        if (ks < 14) {
            const int bn = (ks + 2) % 3;
            const unsigned short* src = gB + (size_t)(ks + 2) * 8192;
            gll16(src,       &Bs[bn][bdst]);
            gll16(src + 512, &Bs[bn][bdst + 512]);
        }
        // build + store A(ks+1) (consumes U(ks+1) loaded at iter ks-1)
        if (ks < 15)
            *(u32x4*)&As[ab ^ 1][swr] = build_e1(uiN, ujN);
        // prefetch U(ks+2) registers
        if (ks < 14) {
            uiN = *(const bf16x8*)(gUi + 32 * (ks + 2));
            ujN = *(const bf16x8*)(gUj + 32 * (ks + 2));
        }

        bf16x8 af[4], bf[4];
        #pragma unroll
        for (int mi = 0; mi < 4; ++mi)
            af[mi] = *(const bf16x8*)&As[ab][ard + mi * 512];
        #pragma unroll
        for (int ni = 0; ni < 4; ++ni)
            bf[ni] = *(const bf16x8*)&Bs[bb][brd + ni * 128];

        __builtin_amdgcn_s_setprio(1);
        #pragma unroll
        for (int ni = 0; ni < 4; ++ni)
            #pragma unroll
            for (int mi = 0; mi < 4; ++mi)
                acc[mi][ni] = __builtin_amdgcn_mfma_f32_16x16x32_bf16(
                    af[mi], bf[ni], acc[mi][ni], 0, 0, 0);
        __builtin_amdgcn_s_setprio(0);

        // counted-vmcnt barrier: keep the 4 newest (B(ks+2)+U(ks+2)) in
        // flight; everything older (incl. B(ks+1)) must be complete.
        if (ks < 14) {
            asm volatile("s_waitcnt vmcnt(4) lgkmcnt(0)\n\ts_barrier" ::: "memory");
        } else if (ks == 14) {
            asm volatile("s_waitcnt vmcnt(0) lgkmcnt(0)\n\ts_barrier" ::: "memory");
        }
        // ks == 15: no barrier needed; epilogue uses only regs + `red`
    }

    // ---- epilogue: relu(+c2), dot E3, 16-lane shuffle reduce, cross-wave LDS
    const float c3v = c3p[0];
    #pragma unroll
    for (int mi = 0; mi < 4; ++mi) {
        #pragma unroll
        for (int r = 0; r < 4; ++r) {
            float part = 0.f;
            #pragma unroll
            for (int ni = 0; ni < 4; ++ni) {
                int g = 64 * wc + 16 * ni + ln;
                float v = fmaxf(acc[mi][ni][r] + c2_s[g], 0.f);
                part = fmaf(v, e3_s[g], part);
            }
            part += __shfl_xor(part, 1);
            part += __shfl_xor(part, 2);
            part += __shfl_xor(part, 4);
            part += __shfl_xor(part, 8);
            if (ln == 0) red[64 * wr + 16 * mi + 4 * hi + r][wc] = part;
        }
    }
    __syncthreads();

    if (tid < PTILE) {
        int p = p0 + tid;
        if (p < NPAIR) {
            float s = red[tid][0] + red[tid][1] + red[tid][2] + red[tid][3] + c3v;
            outE[(size_t)b * NPAIR + p] = sigmoidf_(s);
        }
    }
}

// ---------------------------------------------------------------------------
extern "C" void kernel_launch(void* const* d_in, const int* in_sizes, int n_in,
                              void* d_out, int out_size, void* d_ws, size_t ws_size,
                              hipStream_t stream)
{
    const float* z  = (const float*)d_in[0];
    const float* W1 = (const float*)d_in[1];
    const float* b1 = (const float*)d_in[2];
    const float* W2 = (const float*)d_in[3];
    const float* b2 = (const float*)d_in[4];
    const float* W3 = (const float*)d_in[5];
    const float* b3 = (const float*)d_in[6];
    const float* E1 = (const float*)d_in[7];
    const float* c1 = (const float*)d_in[8];
    const float* E2 = (const float*)d_in[9];
    const float* c2 = (const float*)d_in[10];
    const float* E3 = (const float*)d_in[11];
    const float* c3 = (const float*)d_in[12];

    float* out = (float*)d_out;
    float* ws  = (float*)d_ws;

    // workspace layout
    float* h1  = ws;                        // 128*512 f32
    float* h2  = h1 + 65536;                // 128*512 f32
    float* nf  = h2 + 65536;                // 128*3200 f32
    float* Abc = nf + 409600;               // 128*512 f32
    unsigned short* Uib = (unsigned short*)(Abc + 65536);   // 128*50*512 bf16
    unsigned short* Ujb = Uib + (size_t)BATCH * MAXN * 512; // 128*50*512 bf16
    unsigned short* E2t = Ujb + (size_t)BATCH * MAXN * 512; // 64*256*8 bf16

    dim3 blk(256);

    // h1, Abc, E2t
    prologue_a<<<dim3(48, 2), blk, 0, stream>>>(z, W1, b1, E1, c1, E2, E2t, h1, Abc);

    // h2 = relu(h1@W2^T+b2)   (32 blocks)
    gemm_nt32<1><<<dim3(8, 4), blk, 0, stream>>>(
        h1, HIDDEN, W2, HIDDEN, b2, h2, HIDDEN, nullptr, HIDDEN);

    // nf raw -> ws ; sigmoid(nf) -> out   (200 blocks)
    gemm_nt32<2><<<dim3(50, 4), blk, 0, stream>>>(
        h2, HIDDEN, W3, HIDDEN, b3, nf, 3200, out, HIDDEN);

    // Ui' = bf16(nf@E1i^T + Abc) ; Uj = bf16(nf@E1j^T)
    uiuj_gemm<<<dim3(16, 100), blk, 0, stream>>>(nf, E1, Abc, Uib, Ujb);

    // fused edge MLP with MFMA
    edge_mfma<<<dim3(NTILES, BATCH), dim3(512), 0, stream>>>(
        Uib, Ujb, E2t, c2, E3, c3, out + BATCH * MAXN * NFD);
}